// Round 10
// baseline (1836.932 us; speedup 1.0000x reference)
//
#include <hip/hip_runtime.h>
#include <stdint.h>

#define T_SEQ  1132
#define BATCH  128
#define HID    13
#define G4     52
#define NLAYER 100
#define NPIPE  8            // pipelines, 16 batch each
#define LPW    10           // compute waves (layers) per WG
#define NWGP   10           // WGs per pipeline (NLAYER/LPW)
#define NTHR   768          // 12 waves: 0..9 compute, 10 DMA-in, 11 DMA-out
#define CH     4            // timesteps per chunk (1132 = 4*283, no tail)
#define NCH    283
#define RCL    2            // intra-WG LDS chunk slots (power of 2)
#define RC     4            // global ring chunk slots (power of 2)
#define WBH    (16*HID)     // 208
#define PLANE  (CH*256)     // 1024 shorts per plane
#define CHUNK_U32 1024      // ring u32 per chunk: hi-plane 512u32 | lo-plane 512u32
#define NCLS   10
#define FEAT   (T_SEQ*HID)

#define FLAG_BYTES 65536
#define RING_U32_PER_WG ((size_t)RC * CHUNK_U32)
#define RING_BYTES ((size_t)(NPIPE*NWGP) * RING_U32_PER_WG * 4)

typedef float f32x4 __attribute__((ext_vector_type(4)));
typedef short s16x8 __attribute__((ext_vector_type(8)));

__device__ __forceinline__ float sigm(float x) {
  return __builtin_amdgcn_rcpf(1.0f + __expf(-x));
}
__device__ __forceinline__ float tanh_(float x) {
  return 1.0f - 2.0f * __builtin_amdgcn_rcpf(1.0f + __expf(2.0f * x));
}

__device__ __forceinline__ void bf16split(float x, short& hi, short& lo) {
  union { float f; unsigned u; } a; a.f = x;
  unsigned hu = a.u & 0xFFFF0000u;
  hi = (short)(hu >> 16);
  union { float f; unsigned u; } h; h.u = hu;
  union { float f; unsigned u; } r; r.f = x - h.f;
  lo = (short)(r.u >> 16);
}

__device__ __forceinline__ void lspin_ge(int* p, int need) {
  int v = __hip_atomic_load(p, __ATOMIC_ACQUIRE, __HIP_MEMORY_SCOPE_WORKGROUP);
  while (v < need) {
    __builtin_amdgcn_s_sleep(1);
    v = __hip_atomic_load(p, __ATOMIC_ACQUIRE, __HIP_MEMORY_SCOPE_WORKGROUP);
  }
}
__device__ __forceinline__ void gspin_ge(int* p, int need) {
  int v = __hip_atomic_load(p, __ATOMIC_RELAXED, __HIP_MEMORY_SCOPE_AGENT);
  while (v < need) {
    __builtin_amdgcn_s_sleep(1);
    v = __hip_atomic_load(p, __ATOMIC_RELAXED, __HIP_MEMORY_SCOPE_AGENT);
  }
}

// 8 pipelines x 16 batch; WG = 10 consecutive layers (waves 0-9)
// + DMA-in wave (10) + DMA-out wave (11). 90/100 layer hops are LDS-local;
// 10 cross-WG hops via LLC ring, each owned by dedicated DMA waves.
__global__ __launch_bounds__(NTHR) void lstm_pipeline(
    const float* __restrict__ xin,   // [BATCH][T][HID]
    const float* __restrict__ w_ih,  // [L][G4][HID]
    const float* __restrict__ w_hh,  // [L][G4][HID]
    const float* __restrict__ b_ih,  // [L][G4]
    const float* __restrict__ b_hh,  // [L][G4]
    int*      flags,
    uint32_t* ring,
    float*    act)                   // [T][BATCH*HID]
{
  const int wg   = blockIdx.x;
  const int pp   = wg / NWGP;
  const int wgi  = wg - pp * NWGP;
  const int tid  = threadIdx.x;
  const int lane = tid & 63;
  const int nt   = tid >> 6;           // 0..9 compute, 10 DMA-in, 11 DMA-out
  const int quad = lane >> 4;
  const int j    = lane & 15;
  const bool lastWG = (wgi == NWGP - 1);

  __shared__ __align__(16) short sXP[LPW][RCL][2][PLANE];  // staging [hi|lo]
  __shared__ __align__(16) short sHh[LPW][16][16];
  __shared__ __align__(16) short sHl[LPW][16][16];
  __shared__ __align__(16) uint32_t sOutR[RCL][CHUNK_U32]; // wave9 -> DMA-out
  __shared__ int sProg[LPW];   // chunks staged for wave c
  __shared__ int sCons[LPW];   // chunks consumed by wave c
  __shared__ int sProgOut;     // chunks wave9 wrote to sOutR
  __shared__ int sConsOut;     // chunks DMA-out flushed

  int* flReadySelf = flags + ((pp * NWGP + wgi) * 2 + 0) * 16;
  int* flProgSelf  = flags + ((pp * NWGP + wgi) * 2 + 1) * 16;
  int* flReadyPrev = (wgi > 0) ? flags + ((pp * NWGP + wgi - 1) * 2 + 0) * 16 : flags;
  int* flProgNext  = (!lastWG) ? flags + ((pp * NWGP + wgi + 1) * 2 + 1) * 16 : flags;

  if (lane == 0) {
    if (nt == 11)
      __hip_atomic_store(flReadySelf, 0, __ATOMIC_RELAXED, __HIP_MEMORY_SCOPE_AGENT);
    if (nt == 10)
      __hip_atomic_store(flProgSelf, 0, __ATOMIC_RELAXED, __HIP_MEMORY_SCOPE_AGENT);
  }

  for (int i = tid; i < LPW * RCL * 2 * PLANE; i += NTHR) ((short*)sXP)[i] = 0;
  for (int i = tid; i < LPW * 256; i += NTHR) { ((short*)sHh)[i] = 0; ((short*)sHl)[i] = 0; }
  for (int i = tid; i < RCL * CHUNK_U32; i += NTHR) ((uint32_t*)sOutR)[i] = 0;
  if (tid < LPW) { sProg[tid] = 0; sCons[tid] = 0; }
  if (tid == 0) { sProgOut = 0; sConsOut = 0; }
  __syncthreads();   // the only barrier; waves free-run after this

  if (nt < LPW) {
    // ================= compute wave: layer l =================
    const int l = wgi * LPW + nt;
    const bool lastL = (l == NLAYER - 1);

    s16x8 Bh[4], Bl[4];
    float bq[4];
    #pragma unroll
    for (int q = 0; q < 4; ++q) {
      #pragma unroll
      for (int jj = 0; jj < 8; ++jj) {
        int k = quad * 8 + jj;
        float w = 0.f;
        if (j < HID) {
          int g = q * HID + j;
          if (k < HID)                      w = w_ih[(size_t)(l * G4 + g) * HID + k];
          else if (k >= 16 && k < 16 + HID) w = w_hh[(size_t)(l * G4 + g) * HID + (k - 16)];
        }
        short hi, lo; bf16split(w, hi, lo);
        Bh[q][jj] = hi; Bl[q][jj] = lo;
      }
      bq[q] = (j < HID) ? (b_ih[l * G4 + q * HID + j] + b_hh[l * G4 + q * HID + j]) : 0.f;
    }

    float cstate[4] = {0.f, 0.f, 0.f, 0.f};

    #pragma unroll 1
    for (int ci = 0; ci < NCH; ++ci) {
      const int slot = ci & (RCL - 1);

      lspin_ge(&sProg[nt], ci + 1);                 // input chunk ready
      if (ci + 1 - RCL > 0) {                       // output slot free
        if (nt < LPW - 1) lspin_ge(&sCons[nt + 1], ci + 1 - RCL);
        else              lspin_ge(&sConsOut,       ci + 1 - RCL);
      }

      const short* xh = &sXP[nt][slot][0][0];
      const short* xl = &sXP[nt][slot][1][0];

      #pragma unroll
      for (int s = 0; s < CH; ++s) {
        const short* ph = (quad < 2) ? &xh[s * 256 + j * 16 + quad * 8] : &sHh[nt][j][(quad - 2) * 8];
        const short* pl = (quad < 2) ? &xl[s * 256 + j * 16 + quad * 8] : &sHl[nt][j][(quad - 2) * 8];
        s16x8 Azh = *(const s16x8*)ph;
        s16x8 Azl = *(const s16x8*)pl;

        f32x4 acc[4];
        #pragma unroll
        for (int q = 0; q < 4; ++q) {
          f32x4 a = { bq[q], bq[q], bq[q], bq[q] };
          a = __builtin_amdgcn_mfma_f32_16x16x32_bf16(Azh, Bh[q], a, 0, 0, 0);
          a = __builtin_amdgcn_mfma_f32_16x16x32_bf16(Azh, Bl[q], a, 0, 0, 0);
          a = __builtin_amdgcn_mfma_f32_16x16x32_bf16(Azl, Bh[q], a, 0, 0, 0);
          acc[q] = a;
        }

        if (j < HID) {
          #pragma unroll
          for (int r = 0; r < 4; ++r) {
            float gi = acc[0][r], gf = acc[1][r], gg = acc[2][r], go = acc[3][r];
            float cn_ = sigm(gf) * cstate[r] + sigm(gi) * tanh_(gg);
            cstate[r] = cn_;
            float hn = sigm(go) * tanh_(cn_);
            short hi, lo; bf16split(hn, hi, lo);
            int br = quad * 4 + r;
            sHh[nt][br][j] = hi;
            sHl[nt][br][j] = lo;
            if (nt < LPW - 1) {
              sXP[nt + 1][slot][0][s * 256 + br * 16 + j] = hi;
              sXP[nt + 1][slot][1][s * 256 + br * 16 + j] = lo;
            } else if (!lastL) {
              short* so = (short*)&sOutR[slot][0];
              so[s * 256 + br * 16 + j]         = hi;   // hi-plane
              so[PLANE + s * 256 + br * 16 + j] = lo;   // lo-plane
            } else {
              sOutR[slot][s * WBH + br * HID + j] = __float_as_uint(hn);
            }
          }
        }
      }

      if (lane == 0) {
        __hip_atomic_store(&sCons[nt], ci + 1, __ATOMIC_RELEASE, __HIP_MEMORY_SCOPE_WORKGROUP);
        if (nt < LPW - 1)
          __hip_atomic_store(&sProg[nt + 1], ci + 1, __ATOMIC_RELEASE, __HIP_MEMORY_SCOPE_WORKGROUP);
        else
          __hip_atomic_store(&sProgOut, ci + 1, __ATOMIC_RELEASE, __HIP_MEMORY_SCOPE_WORKGROUP);
      }
    }
  } else if (nt == 10) {
    // ================= DMA-in wave =================
    const uint32_t* ringprev = ring + (size_t)(pp * NWGP + wgi - 1) * RING_U32_PER_WG;
    const size_t    xbase    = (size_t)(pp * 16) * (T_SEQ * HID);

    int off0[13], xoff[13];
    #pragma unroll
    for (int k = 0; k < 13; ++k) {
      int i = lane + 64 * k;
      int s = i / WBH, r = i - s * WBH;
      int b16 = r / HID, jj = r - b16 * HID;
      off0[k] = s * 256 + b16 * 16 + jj;
      xoff[k] = b16 * (T_SEQ * HID) + s * HID + jj;
    }

    #pragma unroll 1
    for (int cin = 0; cin < NCH; ++cin) {
      const int slot = cin & (RCL - 1);
      if (cin + 1 - RCL > 0) lspin_ge(&sCons[0], cin + 1 - RCL);

      if (wgi > 0) {
        gspin_ge(flReadyPrev, cin + 1);
        const uint32_t* src = ringprev + (size_t)(cin & (RC - 1)) * CHUNK_U32;
        uint32_t v[16];
        #pragma unroll
        for (int k = 0; k < 16; ++k)
          v[k] = __hip_atomic_load(&src[lane + 64 * k], __ATOMIC_RELAXED, __HIP_MEMORY_SCOPE_AGENT);
        uint32_t* dst = (uint32_t*)&sXP[0][slot][0][0];
        #pragma unroll
        for (int k = 0; k < 16; ++k) dst[lane + 64 * k] = v[k];
        asm volatile("s_waitcnt vmcnt(0)" ::: "memory");   // loads landed -> slot consumed
        if (lane == 0)
          __hip_atomic_store(flProgSelf, cin + 1, __ATOMIC_RELAXED, __HIP_MEMORY_SCOPE_AGENT);
      } else {
        float v[13];
        #pragma unroll
        for (int k = 0; k < 13; ++k)
          v[k] = xin[xbase + xoff[k] + (size_t)(cin * CH) * HID];
        #pragma unroll
        for (int k = 0; k < 13; ++k) {
          short hi, lo; bf16split(v[k], hi, lo);
          sXP[0][slot][0][off0[k]] = hi;
          sXP[0][slot][1][off0[k]] = lo;
        }
      }
      if (lane == 0)
        __hip_atomic_store(&sProg[0], cin + 1, __ATOMIC_RELEASE, __HIP_MEMORY_SCOPE_WORKGROUP);
    }
  } else {
    // ================= DMA-out wave =================
    uint32_t* ringmine = ring + (size_t)(pp * NWGP + wgi) * RING_U32_PER_WG;

    int aoff[13];
    #pragma unroll
    for (int k = 0; k < 13; ++k) {
      int i = lane + 64 * k;
      int s = i / WBH, r = i - s * WBH;
      aoff[k] = s * (BATCH * HID) + pp * WBH + r;
    }

    #pragma unroll 1
    for (int cout = 0; cout < NCH; ++cout) {
      const int slot = cout & (RCL - 1);
      lspin_ge(&sProgOut, cout + 1);

      if (!lastWG) {
        if (cout + 1 - RC > 0) gspin_ge(flProgNext, cout + 1 - RC);
        uint32_t* dst = ringmine + (size_t)(cout & (RC - 1)) * CHUNK_U32;
        uint32_t v[16];
        #pragma unroll
        for (int k = 0; k < 16; ++k) v[k] = sOutR[slot][lane + 64 * k];
        // LDS reads complete before the release store below (lgkmcnt); slot reusable
        if (lane == 0)
          __hip_atomic_store(&sConsOut, cout + 1, __ATOMIC_RELEASE, __HIP_MEMORY_SCOPE_WORKGROUP);
        #pragma unroll
        for (int k = 0; k < 16; ++k)
          __hip_atomic_store(&dst[lane + 64 * k], v[k],
                             __ATOMIC_RELAXED, __HIP_MEMORY_SCOPE_AGENT);
        asm volatile("s_waitcnt vmcnt(0)" ::: "memory");
        if (lane == 0)
          __hip_atomic_store(flReadySelf, cout + 1, __ATOMIC_RELAXED, __HIP_MEMORY_SCOPE_AGENT);
      } else {
        const size_t abase = (size_t)(cout * CH) * (BATCH * HID);
        float v[13];
        #pragma unroll
        for (int k = 0; k < 13; ++k) v[k] = __uint_as_float(sOutR[slot][lane + 64 * k]);
        if (lane == 0)
          __hip_atomic_store(&sConsOut, cout + 1, __ATOMIC_RELEASE, __HIP_MEMORY_SCOPE_WORKGROUP);
        #pragma unroll
        for (int k = 0; k < 13; ++k)
          act[abase + aoff[k]] = v[k];
      }
    }
  }
}

__global__ __launch_bounds__(256) void linear_softmax(
    const float* __restrict__ act,    // [T][BATCH*HID]
    const float* __restrict__ w_lin,  // [NCLS][FEAT]
    const float* __restrict__ b_lin,
    float* __restrict__ out)          // [BATCH][NCLS]
{
  const int b   = blockIdx.x;
  const int tid = threadIdx.x;
  float accv[NCLS];
  #pragma unroll
  for (int c = 0; c < NCLS; ++c) accv[c] = 0.f;

  for (int i = tid; i < FEAT; i += 256) {
    int t = i / HID; int jj = i - t * HID;
    float a = act[(size_t)t * (BATCH * HID) + b * HID + jj];
    #pragma unroll
    for (int c = 0; c < NCLS; ++c)
      accv[c] += a * w_lin[(size_t)c * FEAT + i];
  }

  __shared__ float red[NCLS][256];
  #pragma unroll
  for (int c = 0; c < NCLS; ++c) red[c][tid] = accv[c];
  __syncthreads();
  for (int off = 128; off > 0; off >>= 1) {
    if (tid < off) {
      #pragma unroll
      for (int c = 0; c < NCLS; ++c) red[c][tid] += red[c][tid + off];
    }
    __syncthreads();
  }
  if (tid == 0) {
    float lg[NCLS]; float mx = -1e30f;
    #pragma unroll
    for (int c = 0; c < NCLS; ++c) { lg[c] = red[c][0] + b_lin[c]; mx = fmaxf(mx, lg[c]); }
    float sum = 0.f;
    #pragma unroll
    for (int c = 0; c < NCLS; ++c) { lg[c] = __expf(lg[c] - mx); sum += lg[c]; }
    float inv = 1.0f / sum;
    #pragma unroll
    for (int c = 0; c < NCLS; ++c) out[b * NCLS + c] = lg[c] * inv;
  }
}

extern "C" void kernel_launch(void* const* d_in, const int* in_sizes, int n_in,
                              void* d_out, int out_size, void* d_ws, size_t ws_size,
                              hipStream_t stream) {
  const float* xin  = (const float*)d_in[0];
  const float* wih  = (const float*)d_in[1];
  const float* whh  = (const float*)d_in[2];
  const float* bih  = (const float*)d_in[3];
  const float* bhh  = (const float*)d_in[4];
  const float* wlin = (const float*)d_in[5];
  const float* blin = (const float*)d_in[6];

  char*     ws    = (char*)d_ws;
  int*      flags = (int*)ws;
  uint32_t* ring  = (uint32_t*)(ws + FLAG_BYTES);
  float*    act   = (float*)(ws + FLAG_BYTES + RING_BYTES);

  lstm_pipeline<<<NPIPE * NWGP, NTHR, 0, stream>>>(xin, wih, whh, bih, bhh, flags, ring, act);
  linear_softmax<<<BATCH, 256, 0, stream>>>(act, wlin, blin, (float*)d_out);
}

// Round 11
// 983.515 us; speedup vs baseline: 1.8677x; 1.8677x over previous
//
#include <hip/hip_runtime.h>
#include <stdint.h>

#define T_SEQ  1132
#define BATCH  128
#define HID    13
#define G4     52
#define NLAYER 100
#define NPIPE  8            // pipelines, 16 batch each
#define LPW    4            // compute waves (layers) per WG
#define NWGP   25           // WGs per pipeline
#define NTHR   384          // 6 waves: 0..3 compute, 4 DMA-in, 5 DMA-out
#define CH     4            // timesteps per chunk (1132 = 4*283)
#define NCH    283
#define RCL    4            // LDS staging slots (power of 2)
#define RC     8            // global ring chunk slots (power of 2)
#define NCLS   10
#define FEAT   (T_SEQ*HID)

#define CHUNK_U32 (CH*256)  // 1024 u32 per chunk (64 lanes x 16B x CH)
#define FLAG_BYTES 65536
#define RING_U32_PER_WG ((size_t)RC * CHUNK_U32)
#define RING_BYTES ((size_t)(NPIPE*NWGP) * RING_U32_PER_WG * 4)

typedef float  f32x4 __attribute__((ext_vector_type(4)));
typedef __fp16 f16x4 __attribute__((ext_vector_type(4)));
typedef unsigned int u32x4 __attribute__((ext_vector_type(4)));

struct HL { f16x4 h; f16x4 l; };   // 16B: hi-halves | lo-halves

__device__ __forceinline__ float sigm(float x) {
  return __builtin_amdgcn_rcpf(1.0f + __expf(-x));
}
__device__ __forceinline__ float tanh_(float x) {
  return 1.0f - 2.0f * __builtin_amdgcn_rcpf(1.0f + __expf(2.0f * x));
}
// f16 hi/lo split: ~22 effective mantissa bits
__device__ __forceinline__ void f16split(float x, __fp16& hi, __fp16& lo) {
  hi = (__fp16)x;
  lo = (__fp16)(x - (float)hi);
}

__device__ __forceinline__ void lspin_ge(int* p, int need) {
  int v = __hip_atomic_load(p, __ATOMIC_ACQUIRE, __HIP_MEMORY_SCOPE_WORKGROUP);
  while (v < need) {
    __builtin_amdgcn_s_sleep(1);
    v = __hip_atomic_load(p, __ATOMIC_ACQUIRE, __HIP_MEMORY_SCOPE_WORKGROUP);
  }
}
__device__ __forceinline__ void gspin_ge(int* p, int need) {
  int v = __hip_atomic_load(p, __ATOMIC_RELAXED, __HIP_MEMORY_SCOPE_AGENT);
  while (v < need) {
    __builtin_amdgcn_s_sleep(1);
    v = __hip_atomic_load(p, __ATOMIC_RELAXED, __HIP_MEMORY_SCOPE_AGENT);
  }
}

// D[gate'][batch] orientation: A = weights (rows m~=lane&15 = gate-in-tile,
// k=quad*4+jj), B = Z (k=quad*4+jj, col=batch=lane&15). D: row=quad*4+reg,
// col=lane&15. Lane (quad,b) owns cells j~=4quad+r of batch b; the cell update
// writes next step's B-fragment IN REGISTERS (same lane) — no LDS round-trip
// on the h-recurrence. Handoff to next layer: one ds_write_b128 per lane/step,
// lane-contiguous (conflict-free), identical layout consumed as the x B-frag.
__global__ __launch_bounds__(NTHR) void lstm_pipeline(
    const float* __restrict__ xin,   // [BATCH][T][HID]
    const float* __restrict__ w_ih,  // [L][G4][HID]
    const float* __restrict__ w_hh,  // [L][G4][HID]
    const float* __restrict__ b_ih,  // [L][G4]
    const float* __restrict__ b_hh,  // [L][G4]
    int*      flags,
    uint32_t* ring,
    float*    act)                   // [T][BATCH*HID]
{
  const int wg   = blockIdx.x;
  const int pp   = wg / NWGP;
  const int wgi  = wg - pp * NWGP;
  const int tid  = threadIdx.x;
  const int lane = tid & 63;
  const int nt   = tid >> 6;           // 0..3 compute, 4 DMA-in, 5 DMA-out
  const int quad = lane >> 4;
  const int b15  = lane & 15;          // batch column / A-row within tile
  const bool lastWG = (wgi == NWGP - 1);

  // staging: [layer][slot][step][256 u32] ; each lane owns u32[lane*4..+3] = HL
  __shared__ __align__(16) uint32_t sXP[LPW][RCL][CH][256];   // 64 KB
  __shared__ __align__(16) uint32_t sOutR[RCL][CH][256];      // 16 KB
  __shared__ int sProg[LPW];
  __shared__ int sCons[LPW];
  __shared__ int sProgOut;
  __shared__ int sConsOut;

  int* flReadySelf = flags + ((pp * NWGP + wgi) * 2 + 0) * 16;
  int* flProgSelf  = flags + ((pp * NWGP + wgi) * 2 + 1) * 16;
  int* flReadyPrev = (wgi > 0) ? flags + ((pp * NWGP + wgi - 1) * 2 + 0) * 16 : flags;
  int* flProgNext  = (!lastWG) ? flags + ((pp * NWGP + wgi + 1) * 2 + 1) * 16 : flags;

  if (lane == 0) {
    if (nt == LPW + 1)  // DMA-out owns the "my chunks published" flag
      __hip_atomic_store(flReadySelf, 0, __ATOMIC_RELAXED, __HIP_MEMORY_SCOPE_AGENT);
    if (nt == LPW)      // DMA-in owns the "prev ring consumed" flag
      __hip_atomic_store(flProgSelf, 0, __ATOMIC_RELAXED, __HIP_MEMORY_SCOPE_AGENT);
  }
  if (tid < LPW) { sProg[tid] = 0; sCons[tid] = 0; }
  if (tid == 0) { sProgOut = 0; sConsOut = 0; }
  __syncthreads();   // the only barrier; waves free-run after this

  if (nt < LPW) {
    // ================= compute wave: layer l =================
    const int l = wgi * LPW + nt;
    const bool lastL = (l == NLAYER - 1);

    // Static A-fragments (f16 hi/lo): Wx and Wh, 4 gate-type tiles.
    // A[m~ = b15][k = quad*4+jj]; original gate row g = mt*13 + m~ (m~<13).
    f16x4 Axh[4], Axl[4], Ahh[4], Ahl[4];
    f32x4 biasv[4];
    #pragma unroll
    for (int mt = 0; mt < 4; ++mt) {
      #pragma unroll
      for (int jj = 0; jj < 4; ++jj) {
        int k = quad * 4 + jj;
        float wx = 0.f, wh = 0.f;
        if (b15 < HID && k < HID) {
          int g = mt * HID + b15;
          wx = w_ih[(size_t)(l * G4 + g) * HID + k];
          wh = w_hh[(size_t)(l * G4 + g) * HID + k];
        }
        __fp16 hi, lo;
        f16split(wx, hi, lo); Axh[mt][jj] = hi; Axl[mt][jj] = lo;
        f16split(wh, hi, lo); Ahh[mt][jj] = hi; Ahl[mt][jj] = lo;
      }
      #pragma unroll
      for (int r = 0; r < 4; ++r) {
        int jt = quad * 4 + r;   // cell row j~
        biasv[mt][r] = (jt < HID)
            ? (b_ih[l * G4 + mt * HID + jt] + b_hh[l * G4 + mt * HID + jt]) : 0.f;
      }
    }

    f16x4 Bhh = (f16x4)0, Bhl = (f16x4)0;   // h B-frag (own registers)
    float cst[4] = {0.f, 0.f, 0.f, 0.f};

    #pragma unroll 1
    for (int ci = 0; ci < NCH; ++ci) {
      const int slot = ci & (RCL - 1);

      lspin_ge(&sProg[nt], ci + 1);                 // input staged
      if (ci + 1 - RCL > 0) {                       // output slot free
        if (nt < LPW - 1) lspin_ge(&sCons[nt + 1], ci + 1 - RCL);
        else              lspin_ge(&sConsOut,       ci + 1 - RCL);
      }

      // ---- x-part precompute (off the h-critical path) ----
      f32x4 ax[CH][4];
      #pragma unroll
      for (int s = 0; s < CH; ++s) {
        u32x4 bx = *(const u32x4*)&sXP[nt][slot][s][lane * 4];
        HL z = __builtin_bit_cast(HL, bx);
        #pragma unroll
        for (int mt = 0; mt < 4; ++mt) {
          f32x4 a = biasv[mt];
          a = __builtin_amdgcn_mfma_f32_16x16x16f16(Axh[mt], z.h, a, 0, 0, 0);
          a = __builtin_amdgcn_mfma_f32_16x16x16f16(Axl[mt], z.h, a, 0, 0, 0);
          a = __builtin_amdgcn_mfma_f32_16x16x16f16(Axh[mt], z.l, a, 0, 0, 0);
          ax[s][mt] = a;
        }
      }
      // input slot consumed (data now in registers)
      if (lane == 0)
        __hip_atomic_store(&sCons[nt], ci + 1, __ATOMIC_RELEASE, __HIP_MEMORY_SCOPE_WORKGROUP);

      // ---- CH steps of the h-recurrence (register-resident) ----
      #pragma unroll
      for (int s = 0; s < CH; ++s) {
        f32x4 acc[4];
        #pragma unroll
        for (int mt = 0; mt < 4; ++mt) {
          f32x4 a = ax[s][mt];
          a = __builtin_amdgcn_mfma_f32_16x16x16f16(Ahh[mt], Bhh, a, 0, 0, 0);
          a = __builtin_amdgcn_mfma_f32_16x16x16f16(Ahl[mt], Bhh, a, 0, 0, 0);
          a = __builtin_amdgcn_mfma_f32_16x16x16f16(Ahh[mt], Bhl, a, 0, 0, 0);
          acc[mt] = a;
        }
        float hnv[4];
        #pragma unroll
        for (int r = 0; r < 4; ++r) {
          float gi = acc[0][r], gf = acc[1][r], gg = acc[2][r], go = acc[3][r];
          float c = sigm(gf) * cst[r] + sigm(gi) * tanh_(gg);
          cst[r] = c;
          float h = sigm(go) * tanh_(c);
          hnv[r] = h;
          __fp16 hi, lo; f16split(h, hi, lo);
          Bhh[r] = hi; Bhl[r] = lo;          // next step's B-frag, in place
        }
        // handoff (conflict-free b128, off the recurrence chain)
        if (nt < LPW - 1) {
          HL o; o.h = Bhh; o.l = Bhl;
          *(u32x4*)&sXP[nt + 1][slot][s][lane * 4] = __builtin_bit_cast(u32x4, o);
        } else if (!lastL) {
          HL o; o.h = Bhh; o.l = Bhl;
          *(u32x4*)&sOutR[slot][s][lane * 4] = __builtin_bit_cast(u32x4, o);
        } else {
          u32x4 w;
          #pragma unroll
          for (int r = 0; r < 4; ++r) w[r] = __float_as_uint(hnv[r]);
          *(u32x4*)&sOutR[slot][s][lane * 4] = w;
        }
      }

      if (lane == 0) {
        if (nt < LPW - 1)
          __hip_atomic_store(&sProg[nt + 1], ci + 1, __ATOMIC_RELEASE, __HIP_MEMORY_SCOPE_WORKGROUP);
        else
          __hip_atomic_store(&sProgOut, ci + 1, __ATOMIC_RELEASE, __HIP_MEMORY_SCOPE_WORKGROUP);
      }
    }
  } else if (nt == LPW) {
    // ================= DMA-in wave =================
    const uint32_t* ringprev = ring + (size_t)(pp * NWGP + wgi - 1) * RING_U32_PER_WG;
    const size_t    xrow     = (size_t)(pp * 16 + b15) * (T_SEQ * HID);

    #pragma unroll 1
    for (int cin = 0; cin < NCH; ++cin) {
      const int slot = cin & (RCL - 1);
      if (cin + 1 - RCL > 0) lspin_ge(&sCons[0], cin + 1 - RCL);

      if (wgi > 0) {
        gspin_ge(flReadyPrev, cin + 1);
        const uint32_t* src = ringprev + (size_t)(cin & (RC - 1)) * CHUNK_U32;
        uint32_t v[CH][4];
        #pragma unroll
        for (int s = 0; s < CH; ++s)
          #pragma unroll
          for (int w = 0; w < 4; ++w)
            v[s][w] = __hip_atomic_load(&src[s * 256 + lane * 4 + w],
                                        __ATOMIC_RELAXED, __HIP_MEMORY_SCOPE_AGENT);
        #pragma unroll
        for (int s = 0; s < CH; ++s) {
          u32x4 q = { v[s][0], v[s][1], v[s][2], v[s][3] };
          *(u32x4*)&sXP[0][slot][s][lane * 4] = q;
        }
        asm volatile("s_waitcnt vmcnt(0)" ::: "memory");   // ring loads landed
        if (lane == 0)
          __hip_atomic_store(flProgSelf, cin + 1, __ATOMIC_RELAXED, __HIP_MEMORY_SCOPE_AGENT);
      } else {
        const int t0 = cin * CH;
        #pragma unroll
        for (int s = 0; s < CH; ++s) {
          HL o;
          #pragma unroll
          for (int jj = 0; jj < 4; ++jj) {
            int k = quad * 4 + jj;
            float v = (k < HID) ? xin[xrow + (size_t)(t0 + s) * HID + k] : 0.f;
            __fp16 hi, lo; f16split(v, hi, lo);
            o.h[jj] = hi; o.l[jj] = lo;
          }
          *(u32x4*)&sXP[0][slot][s][lane * 4] = __builtin_bit_cast(u32x4, o);
        }
      }
      if (lane == 0)
        __hip_atomic_store(&sProg[0], cin + 1, __ATOMIC_RELEASE, __HIP_MEMORY_SCOPE_WORKGROUP);
    }
  } else {
    // ================= DMA-out wave =================
    uint32_t* ringmine = ring + (size_t)(pp * NWGP + wgi) * RING_U32_PER_WG;

    #pragma unroll 1
    for (int cout = 0; cout < NCH; ++cout) {
      const int slot = cout & (RCL - 1);
      lspin_ge(&sProgOut, cout + 1);

      if (!lastWG) {
        if (cout + 1 - RC > 0) gspin_ge(flProgNext, cout + 1 - RC);
        uint32_t* dst = ringmine + (size_t)(cout & (RC - 1)) * CHUNK_U32;
        #pragma unroll
        for (int s = 0; s < CH; ++s) {
          u32x4 v = *(const u32x4*)&sOutR[slot][s][lane * 4];
          #pragma unroll
          for (int w = 0; w < 4; ++w)
            __hip_atomic_store(&dst[s * 256 + lane * 4 + w], v[w],
                               __ATOMIC_RELAXED, __HIP_MEMORY_SCOPE_AGENT);
        }
        asm volatile("s_waitcnt vmcnt(0)" ::: "memory");
        if (lane == 0) {
          __hip_atomic_store(flReadySelf, cout + 1, __ATOMIC_RELAXED, __HIP_MEMORY_SCOPE_AGENT);
          __hip_atomic_store(&sConsOut, cout + 1, __ATOMIC_RELEASE, __HIP_MEMORY_SCOPE_WORKGROUP);
        }
      } else {
        const int t0 = cout * CH;
        #pragma unroll
        for (int s = 0; s < CH; ++s) {
          u32x4 v = *(const u32x4*)&sOutR[slot][s][lane * 4];
          float* dst = act + (size_t)(t0 + s) * (BATCH * HID)
                     + (size_t)(pp * 16 + b15) * HID + quad * 4;
          #pragma unroll
          for (int r = 0; r < 4; ++r)
            if (quad * 4 + r < HID) dst[r] = __uint_as_float(v[r]);
        }
        if (lane == 0)
          __hip_atomic_store(&sConsOut, cout + 1, __ATOMIC_RELEASE, __HIP_MEMORY_SCOPE_WORKGROUP);
      }
    }
  }
}

__global__ __launch_bounds__(256) void linear_softmax(
    const float* __restrict__ act,    // [T][BATCH*HID]
    const float* __restrict__ w_lin,  // [NCLS][FEAT]
    const float* __restrict__ b_lin,
    float* __restrict__ out)          // [BATCH][NCLS]
{
  const int b   = blockIdx.x;
  const int tid = threadIdx.x;
  float accv[NCLS];
  #pragma unroll
  for (int c = 0; c < NCLS; ++c) accv[c] = 0.f;

  for (int i = tid; i < FEAT; i += 256) {
    int t = i / HID; int jj = i - t * HID;
    float a = act[(size_t)t * (BATCH * HID) + b * HID + jj];
    #pragma unroll
    for (int c = 0; c < NCLS; ++c)
      accv[c] += a * w_lin[(size_t)c * FEAT + i];
  }

  __shared__ float red[NCLS][256];
  #pragma unroll
  for (int c = 0; c < NCLS; ++c) red[c][tid] = accv[c];
  __syncthreads();
  for (int off = 128; off > 0; off >>= 1) {
    if (tid < off) {
      #pragma unroll
      for (int c = 0; c < NCLS; ++c) red[c][tid] += red[c][tid + off];
    }
    __syncthreads();
  }
  if (tid == 0) {
    float lg[NCLS]; float mx = -1e30f;
    #pragma unroll
    for (int c = 0; c < NCLS; ++c) { lg[c] = red[c][0] + b_lin[c]; mx = fmaxf(mx, lg[c]); }
    float sum = 0.f;
    #pragma unroll
    for (int c = 0; c < NCLS; ++c) { lg[c] = __expf(lg[c] - mx); sum += lg[c]; }
    float inv = 1.0f / sum;
    #pragma unroll
    for (int c = 0; c < NCLS; ++c) out[b * NCLS + c] = lg[c] * inv;
  }
}

extern "C" void kernel_launch(void* const* d_in, const int* in_sizes, int n_in,
                              void* d_out, int out_size, void* d_ws, size_t ws_size,
                              hipStream_t stream) {
  const float* xin  = (const float*)d_in[0];
  const float* wih  = (const float*)d_in[1];
  const float* whh  = (const float*)d_in[2];
  const float* bih  = (const float*)d_in[3];
  const float* bhh  = (const float*)d_in[4];
  const float* wlin = (const float*)d_in[5];
  const float* blin = (const float*)d_in[6];

  char*     ws    = (char*)d_ws;
  int*      flags = (int*)ws;
  uint32_t* ring  = (uint32_t*)(ws + FLAG_BYTES);
  float*    act   = (float*)(ws + FLAG_BYTES + RING_BYTES);

  lstm_pipeline<<<NPIPE * NWGP, NTHR, 0, stream>>>(xin, wih, whh, bih, bhh, flags, ring, act);
  linear_softmax<<<BATCH, 256, 0, stream>>>(act, wlin, blin, (float*)d_out);
}